// Round 2
// baseline (4271.059 us; speedup 1.0000x reference)
//
#include <hip/hip_runtime.h>
#include <hip/hip_bf16.h>

typedef __attribute__((ext_vector_type(8))) short bf16x8;
typedef __attribute__((ext_vector_type(4))) short short4v;
typedef __attribute__((ext_vector_type(4))) float f32x4;

#define DEVFN __device__ __forceinline__

DEVFN short f2bf(float f){
  __hip_bfloat16 h = __float2bfloat16(f);
  return __builtin_bit_cast(short, h);
}
DEVFN float bf2f(short h){
  return __builtin_bit_cast(float, ((unsigned)(unsigned short)h) << 16);
}

// ---------------- f32 [b][c][n] -> f32 [b][n][c] ----------------
__global__ __launch_bounds__(256) void transpose_k(const float* __restrict__ X,
                                                   float* __restrict__ XT){
  __shared__ float tile[64][65];
  int b = blockIdx.z, c0 = blockIdx.y * 64, n0 = blockIdx.x * 64;
  int t = threadIdx.x, nl = t & 63, cr = t >> 6;
  long base = (long)b * 65536;
#pragma unroll
  for (int i = 0; i < 16; i++){
    int cl = cr + 4 * i;
    tile[cl][nl] = X[base + (c0 + cl) * 256 + (n0 + nl)];
  }
  __syncthreads();
  int cl2 = t & 63, nr2 = t >> 6;
#pragma unroll
  for (int i = 0; i < 16; i++){
    int nl2 = nr2 + 4 * i;
    XT[base + (n0 + nl2) * 256 + (c0 + cl2)] = tile[cl2][nl2];
  }
}

// ---------------- GEMM (f32 in/out, bf16x3 internal): C[m][n] = sum_k A[m][k]*BT[n][k] ----------------
#define EPI_F32       0
#define EPI_BIAS_F32  1
#define EPI_TF32      2
#define EPI_PV_DT     3

template<int EPI>
__global__ __launch_bounds__(256) void gemm_f32(
    const float* __restrict__ A, long sA,
    const float* __restrict__ Bt,
    float* __restrict__ Cf, long sC,
    const float* __restrict__ bias,
    const float* __restrict__ U,
    float* __restrict__ Ot)
{
  __shared__ short Ah[128][72];
  __shared__ short Al[128][72];
  __shared__ short Bh[128][72];
  __shared__ short Bl[128][72];
  int b  = blockIdx.z;
  int m0 = blockIdx.y * 128, n0 = blockIdx.x * 128;
  const float* Ab = A  + (long)b * sA;
  const float* Bb = Bt + (long)b * 65536;
  int t = threadIdx.x;
  int lane = t & 63, wid = t >> 6;
  int wm = (wid >> 1) * 64, wn = (wid & 1) * 64;
  f32x4 acc[4][4] = {};

  for (int kt = 0; kt < 4; kt++){
    int k0 = kt * 64;
    f32x4 va[8], vb[8];
#pragma unroll
    for (int i = 0; i < 8; i++){
      int idx = t + i * 256;
      int r = idx >> 4, kc = (idx & 15) * 4;
      va[i] = *(const f32x4*)(Ab + (m0 + r) * 256 + k0 + kc);
      vb[i] = *(const f32x4*)(Bb + (n0 + r) * 256 + k0 + kc);
    }
    __syncthreads();
#pragma unroll
    for (int i = 0; i < 8; i++){
      int idx = t + i * 256;
      int r = idx >> 4, kc = (idx & 15) * 4;
      short4v ah, al, bh, bl;
#pragma unroll
      for (int j = 0; j < 4; j++){
        float v = va[i][j];
        short h = f2bf(v);
        ah[j] = h; al[j] = f2bf(v - bf2f(h));
        v = vb[i][j];
        h = f2bf(v);
        bh[j] = h; bl[j] = f2bf(v - bf2f(h));
      }
      *(short4v*)(&Ah[r][kc]) = ah;
      *(short4v*)(&Al[r][kc]) = al;
      *(short4v*)(&Bh[r][kc]) = bh;
      *(short4v*)(&Bl[r][kc]) = bl;
    }
    __syncthreads();
#pragma unroll
    for (int ks = 0; ks < 2; ks++){
      bf16x8 afh[4], afl[4], bfh[4], bfl[4];
      int ko = ks * 32 + (lane >> 4) * 8;
#pragma unroll
      for (int mi = 0; mi < 4; mi++){
        afh[mi] = *(const bf16x8*)(&Ah[wm + mi * 16 + (lane & 15)][ko]);
        afl[mi] = *(const bf16x8*)(&Al[wm + mi * 16 + (lane & 15)][ko]);
      }
#pragma unroll
      for (int ni = 0; ni < 4; ni++){
        bfh[ni] = *(const bf16x8*)(&Bh[wn + ni * 16 + (lane & 15)][ko]);
        bfl[ni] = *(const bf16x8*)(&Bl[wn + ni * 16 + (lane & 15)][ko]);
      }
#pragma unroll
      for (int mi = 0; mi < 4; mi++)
#pragma unroll
        for (int ni = 0; ni < 4; ni++){
          acc[mi][ni] = __builtin_amdgcn_mfma_f32_16x16x32_bf16(afh[mi], bfh[ni], acc[mi][ni], 0, 0, 0);
          acc[mi][ni] = __builtin_amdgcn_mfma_f32_16x16x32_bf16(afh[mi], bfl[ni], acc[mi][ni], 0, 0, 0);
          acc[mi][ni] = __builtin_amdgcn_mfma_f32_16x16x32_bf16(afl[mi], bfh[ni], acc[mi][ni], 0, 0, 0);
        }
    }
  }

  int mg0 = m0 + wm + ((lane >> 4) << 2);
  int ng0 = n0 + wn + (lane & 15);
#pragma unroll
  for (int mi = 0; mi < 4; mi++){
#pragma unroll
    for (int ni = 0; ni < 4; ni++){
      int mg = mg0 + mi * 16;
      int ng = ng0 + ni * 16;
      f32x4 v = acc[mi][ni];
      if constexpr (EPI == EPI_F32){
        float* Cb = Cf + (long)b * sC;
#pragma unroll
        for (int r = 0; r < 4; r++) Cb[(mg + r) * 256 + ng] = v[r];
      } else if constexpr (EPI == EPI_BIAS_F32){
        float* Cb = Cf + (long)b * sC;
#pragma unroll
        for (int r = 0; r < 4; r++) Cb[(mg + r) * 256 + ng] = v[r] + bias[mg + r];
      } else if constexpr (EPI == EPI_TF32){
        float* Ob = Ot + (long)b * 65536;
        *(f32x4*)(&Ob[ng * 256 + mg]) = v;
      } else if constexpr (EPI == EPI_PV_DT){
        const float* Ub = U + (long)b * 65536;
        float* Ob = Ot + (long)b * 65536;
        f32x4 p;
#pragma unroll
        for (int r = 0; r < 4; r++) p[r] = Ub[(mg + r) * 256 + ng] - v[r];
        *(f32x4*)(&Ob[ng * 256 + mg]) = p;
      }
    }
  }
}

// ---------------- row softmax in-place over m (last axis); rows are (b,n) ----------------
__global__ __launch_bounds__(256) void softmax_rows_k(float* __restrict__ E){
  int rid = blockIdx.x * 4 + (threadIdx.x >> 6);
  int lane = threadIdx.x & 63;
  int b = rid >> 8, n = rid & 255;
  float* row = E + (long)b * 262144 + n * 256;
  float v[4];
  float mx = -1e30f;
#pragma unroll
  for (int i = 0; i < 4; i++){ v[i] = row[lane + 64 * i]; mx = fmaxf(mx, v[i]); }
  for (int off = 32; off > 0; off >>= 1) mx = fmaxf(mx, __shfl_xor(mx, off));
  float s = 0.f;
#pragma unroll
  for (int i = 0; i < 4; i++){ v[i] = __expf(v[i] - mx); s += v[i]; }
  for (int off = 32; off > 0; off >>= 1) s += __shfl_xor(s, off);
  float inv = 1.f / s;
#pragma unroll
  for (int i = 0; i < 4; i++) row[lane + 64 * i] = v[i] * inv;
}

// ---------------- column sums over n: cs[b][m] = sum_n attn[b][n][m] ----------------
__global__ __launch_bounds__(256) void colsum_k(const float* __restrict__ E, float* __restrict__ cs){
  int b = blockIdx.x, m = threadIdx.x;
  const float* p = E + (long)b * 262144 + m;
  float s = 0.f;
  for (int n = 0; n < 256; n++) s += p[n * 256];
  cs[b * 256 + m] = s;
}

// ---------------- attnT[b][m][n] = attn[b][n][m] / (eps + cs[b][m]), f32 ----------------
__global__ __launch_bounds__(256) void renorm_transpose_k(const float* __restrict__ E,
                                                          const float* __restrict__ cs,
                                                          float* __restrict__ AT){
  __shared__ float tile[64][65];
  int b = blockIdx.z, n0 = blockIdx.y * 64, m0 = blockIdx.x * 64;
  int t = threadIdx.x, ml = t & 63, nr = t >> 6;
  const float* Eb = E + (long)b * 262144;
  float inv = 1.f / (1e-9f + cs[b * 256 + m0 + ml]);
#pragma unroll
  for (int i = 0; i < 16; i++){
    int nl = nr + 4 * i;
    tile[nl][ml] = Eb[(n0 + nl) * 256 + (m0 + ml)] * inv;
  }
  __syncthreads();
  float* Ab = AT + (long)b * 65536;
  int nlw = t & 63, mr = t >> 6;
#pragma unroll
  for (int i = 0; i < 16; i++){
    int mlw = mr + 4 * i;
    Ab[(m0 + mlw) * 256 + (n0 + nlw)] = tile[nlw][mlw];
  }
}

// ---------------- BN stats per channel over (B, N) ----------------
__global__ __launch_bounds__(256) void bn_stats_k(const float* __restrict__ Y,
                                                  float* __restrict__ mean, float* __restrict__ rstd){
  int c = blockIdx.x, t = threadIdx.x;
  float s = 0.f, q = 0.f;
  const float* p = Y + c * 256 + t;
  for (int b = 0; b < 256; b++){ float v = p[(long)b * 65536]; s += v; q += v * v; }
  for (int off = 32; off > 0; off >>= 1){ s += __shfl_down(s, off); q += __shfl_down(q, off); }
  __shared__ float ss[4], qq[4];
  int lane = t & 63, w = t >> 6;
  if (lane == 0){ ss[w] = s; qq[w] = q; }
  __syncthreads();
  if (t == 0){
    float S = ss[0] + ss[1] + ss[2] + ss[3];
    float Q = qq[0] + qq[1] + qq[2] + qq[3];
    float m = S * (1.f / 65536.f);
    float var = Q * (1.f / 65536.f) - m * m;
    mean[c] = m;
    rstd[c] = rsqrtf(var + 1e-5f);
  }
}

// ---------------- BN apply + relu (+2x residual) + layout writes (all f32) ----------------
template<bool RESID, bool WN, bool WT, bool WDOUT>
__global__ __launch_bounds__(256) void bn_apply_k(
    const float* __restrict__ Y, const float* __restrict__ U,
    const float* __restrict__ mean, const float* __restrict__ rstd,
    const float* __restrict__ gamma, const float* __restrict__ beta,
    float* __restrict__ on, float* __restrict__ ot, float* __restrict__ odout)
{
  __shared__ float tile[64][65];
  int b = blockIdx.z, c0 = blockIdx.y * 64, n0 = blockIdx.x * 64;
  int t = threadIdx.x, nl = t & 63, cr = t >> 6;
  long base = (long)b * 65536;
#pragma unroll
  for (int i = 0; i < 16; i++){
    int cl = cr + 4 * i;
    int c = c0 + cl, n = n0 + nl;
    long idx = base + c * 256 + n;
    float y = Y[idx];
    float v = fmaxf((y - mean[c]) * rstd[c] * gamma[c] + beta[c], 0.f);
    if constexpr (RESID) v += 2.f * U[idx];
    if constexpr (WN) on[idx] = v;
    if constexpr (WDOUT) odout[(long)b * 262144 + c * 256 + n] = v;
    if constexpr (WT) tile[cl][nl] = v;
  }
  if constexpr (WT){
    __syncthreads();
    int cl2 = t & 63, nr2 = t >> 6;
#pragma unroll
    for (int i = 0; i < 16; i++){
      int nl2 = nr2 + 4 * i;
      ot[base + (n0 + nl2) * 256 + (c0 + cl2)] = tile[cl2][nl2];
    }
  }
}

extern "C" void kernel_launch(void* const* d_in, const int* in_sizes, int n_in,
                              void* d_out, int out_size, void* d_ws, size_t ws_size,
                              hipStream_t stream)
{
  (void)in_sizes; (void)n_in; (void)out_size; (void)ws_size;

  const float* x0  = (const float*)d_in[0];
  const float* cw  = (const float*)d_in[1];
  const float* bng = (const float*)d_in[2];
  const float* bnb = (const float*)d_in[3];
  const float* wqk = (const float*)d_in[4];
  const float* wv  = (const float*)d_in[5];
  const float* bv  = (const float*)d_in[6];
  const float* wt  = (const float*)d_in[7];
  const float* bt  = (const float*)d_in[8];
  const float* sag = (const float*)d_in[9];
  const float* sab = (const float*)d_in[10];

  const long T = 16777216; // elements per [B,C,N] tensor
  float* F0 = (float*)d_ws;   // x / dT(s=1) / next-x
  float* F1 = F0 + T;         // GEMM f32 out (pre-BN)
  float* F2 = F1 + T;         // x1T / dT(s=0)
  float* U0 = F2 + T;         // current BT operand (uT)
  float* XK = U0 + T;         // xkT, then xv
  float* AT = XK + T;         // attnT
  float* cs = AT + T;
  float* mn = cs + 65536;
  float* rs = mn + 256;
  float* E  = (float*)d_out + 196608; // d_out region 3 (per-batch stripe) as energy scratch

  dim3 thr(256);
  dim3 gg(2, 2, 256);
  dim3 tile(4, 4, 256);

  transpose_k<<<tile, thr, 0, stream>>>(x0, U0);

  // conv0, conv1: x = relu(bn(W x))
  for (int L = 0; L < 2; L++){
    gemm_f32<EPI_F32><<<gg, thr, 0, stream>>>(cw + (long)L * 65536, 0, U0, F1, 65536, nullptr, nullptr, nullptr);
    bn_stats_k<<<256, thr, 0, stream>>>(F1, mn, rs);
    bn_apply_k<false, true, true, false><<<tile, thr, 0, stream>>>(
        F1, nullptr, mn, rs, bng + L * 256, bnb + L * 256, F0, U0, nullptr);
  }

  for (int blk = 0; blk < 4; blk++){
    for (int s = 0; s < 2; s++){
      int li = 2 * blk + s;
      float* u  = (s == 0) ? F0 : F2;  // layer input, [c][n] in layer space
      float* dt = (s == 0) ? F2 : F0;  // scratch for dT
      // xkT = (wqk u)^T
      gemm_f32<EPI_TF32><<<gg, thr, 0, stream>>>(wqk + (long)li * 65536, 0, U0, nullptr, 0, nullptr, nullptr, XK);
      // energy[n][m] = <xk_n, xk_m>
      gemm_f32<EPI_F32><<<gg, thr, 0, stream>>>(XK, 65536, XK, E, 262144, nullptr, nullptr, nullptr);
      softmax_rows_k<<<dim3(16384), thr, 0, stream>>>(E);
      colsum_k<<<dim3(256), thr, 0, stream>>>(E, cs);
      renorm_transpose_k<<<tile, thr, 0, stream>>>(E, cs, AT);
      // xv = wv u + bv  (reuse XK)
      gemm_f32<EPI_BIAS_F32><<<gg, thr, 0, stream>>>(wv + (long)li * 65536, 0, U0, XK, 65536, bv + li * 256, nullptr, nullptr);
      // dT = (u - xv attn')^T
      gemm_f32<EPI_PV_DT><<<gg, thr, 0, stream>>>(XK, 65536, AT, nullptr, 0, nullptr, u, dt);
      // y = wt d + bt
      gemm_f32<EPI_BIAS_F32><<<gg, thr, 0, stream>>>(wt + (long)li * 65536, 0, dt, F1, 65536, bt + li * 256, nullptr, nullptr);
      bn_stats_k<<<256, thr, 0, stream>>>(F1, mn, rs);
      if (s == 0){
        // x1 = 2u + relu(bn(y)); U0 <- x1 (normal = next uT), F2 <- x1T (next u)
        bn_apply_k<true, true, true, false><<<tile, thr, 0, stream>>>(
            F1, u, mn, rs, sag + li * 256, sab + li * 256, U0, F2, nullptr);
      } else {
        // x11pre = 2u + relu(bn(y)); U0 <- (x11pre)^T (conv BT operand)
        bn_apply_k<true, false, true, false><<<tile, thr, 0, stream>>>(
            F1, u, mn, rs, sag + li * 256, sab + li * 256, nullptr, U0, nullptr);
      }
    }
    // block conv + bn + relu -> d_out region blk, F0 (next x), U0 (next xT)
    gemm_f32<EPI_F32><<<gg, thr, 0, stream>>>(cw + (long)(blk + 2) * 65536, 0, U0, F1, 65536, nullptr, nullptr, nullptr);
    bn_stats_k<<<256, thr, 0, stream>>>(F1, mn, rs);
    bn_apply_k<false, true, true, true><<<tile, thr, 0, stream>>>(
        F1, nullptr, mn, rs, bng + (blk + 2) * 256, bnb + (blk + 2) * 256,
        F0, U0, (float*)d_out + blk * 65536);
  }
}

// Round 4
// 2449.487 us; speedup vs baseline: 1.7437x; 1.7437x over previous
//
#include <hip/hip_runtime.h>
#include <hip/hip_bf16.h>

typedef _Float16 f16;
typedef __attribute__((ext_vector_type(8))) _Float16 f16x8;
typedef __attribute__((ext_vector_type(4))) _Float16 f16x4;
typedef __attribute__((ext_vector_type(4))) float f32x4;

// ---------------- f32 -> fp16 cast (weights) ----------------
__global__ __launch_bounds__(256) void cast_f16_k(const float* __restrict__ in,
                                                  f16* __restrict__ out, int n){
  int i = (blockIdx.x * 256 + threadIdx.x) * 4;
  if (i < n){
    f32x4 v = *(const f32x4*)(in + i);
    f16x4 o;
    o[0] = (f16)v[0]; o[1] = (f16)v[1]; o[2] = (f16)v[2]; o[3] = (f16)v[3];
    *(f16x4*)(out + i) = o;
  }
}

// ---------------- f32 [b][c][n] -> fp16 [b][n][c] ----------------
__global__ __launch_bounds__(256) void transpose_f16_k(const float* __restrict__ X,
                                                       f16* __restrict__ XT){
  __shared__ float tile[64][65];
  int b = blockIdx.z, c0 = blockIdx.y * 64, n0 = blockIdx.x * 64;
  int t = threadIdx.x, nl = t & 63, cr = t >> 6;
  long base = (long)b * 65536;
#pragma unroll
  for (int i = 0; i < 16; i++){
    int cl = cr + 4 * i;
    tile[cl][nl] = X[base + (c0 + cl) * 256 + (n0 + nl)];
  }
  __syncthreads();
  int cl2 = t & 63, nr2 = t >> 6;
#pragma unroll
  for (int i = 0; i < 16; i++){
    int nl2 = nr2 + 4 * i;
    XT[base + (n0 + nl2) * 256 + (c0 + cl2)] = (f16)tile[cl2][nl2];
  }
}

// ---------------- GEMM fp16: C[m][n] = sum_k A[m][k] * BT[n][k], 256^3 per batch ----------------
#define EPI_EF32      0
#define EPI_BIAS_F32  1
#define EPI_T16       2
#define EPI_BIAS_F16  3
#define EPI_PV_DT     4

template<int EPI>
__global__ __launch_bounds__(256) void gemm_f16(
    const f16* __restrict__ A, long sA,
    const f16* __restrict__ Bt,
    float* __restrict__ Cf, long sC,
    f16* __restrict__ Oh,
    const float* __restrict__ bias,
    const float* __restrict__ U)
{
  __shared__ f16 As[128][72];
  __shared__ f16 Bs[128][72];
  int b  = blockIdx.z;
  int m0 = blockIdx.y * 128, n0 = blockIdx.x * 128;
  const f16* Ab = A  + (long)b * sA;
  const f16* Bb = Bt + (long)b * 65536;
  int t = threadIdx.x;
  int lane = t & 63, wid = t >> 6;
  int wm = (wid >> 1) * 64, wn = (wid & 1) * 64;
  f32x4 acc[4][4] = {};

  for (int kt = 0; kt < 4; kt++){
    int k0 = kt * 64;
    f16x8 ra[4], rb[4];
#pragma unroll
    for (int i = 0; i < 4; i++){
      int ch = t + i * 256;
      int r = ch >> 3, kc = (ch & 7) * 8;
      ra[i] = *(const f16x8*)(Ab + (m0 + r) * 256 + k0 + kc);
      rb[i] = *(const f16x8*)(Bb + (n0 + r) * 256 + k0 + kc);
    }
    __syncthreads();
#pragma unroll
    for (int i = 0; i < 4; i++){
      int ch = t + i * 256;
      int r = ch >> 3, kc = (ch & 7) * 8;
      *(f16x8*)(&As[r][kc]) = ra[i];
      *(f16x8*)(&Bs[r][kc]) = rb[i];
    }
    __syncthreads();
#pragma unroll
    for (int ks = 0; ks < 2; ks++){
      f16x8 af[4], bfr[4];
      int ko = ks * 32 + (lane >> 4) * 8;
#pragma unroll
      for (int mi = 0; mi < 4; mi++)
        af[mi] = *(const f16x8*)(&As[wm + mi * 16 + (lane & 15)][ko]);
#pragma unroll
      for (int ni = 0; ni < 4; ni++)
        bfr[ni] = *(const f16x8*)(&Bs[wn + ni * 16 + (lane & 15)][ko]);
#pragma unroll
      for (int mi = 0; mi < 4; mi++)
#pragma unroll
        for (int ni = 0; ni < 4; ni++)
          acc[mi][ni] = __builtin_amdgcn_mfma_f32_16x16x32_f16(af[mi], bfr[ni], acc[mi][ni], 0, 0, 0);
    }
  }

  int mg0 = m0 + wm + ((lane >> 4) << 2);
  int ng0 = n0 + wn + (lane & 15);
#pragma unroll
  for (int mi = 0; mi < 4; mi++){
#pragma unroll
    for (int ni = 0; ni < 4; ni++){
      int mg = mg0 + mi * 16;
      int ng = ng0 + ni * 16;
      f32x4 v = acc[mi][ni];
      if constexpr (EPI == EPI_EF32){
        float* Cb = Cf + (long)b * sC;
#pragma unroll
        for (int r = 0; r < 4; r++) Cb[(mg + r) * 256 + ng] = v[r];
      } else if constexpr (EPI == EPI_BIAS_F32){
        float* Cb = Cf + (long)b * sC;
#pragma unroll
        for (int r = 0; r < 4; r++) Cb[(mg + r) * 256 + ng] = v[r] + bias[mg + r];
      } else if constexpr (EPI == EPI_T16){
        f16* Ohb = Oh + (long)b * 65536;
        f16x4 p;
#pragma unroll
        for (int r = 0; r < 4; r++) p[r] = (f16)v[r];
        *(f16x4*)(&Ohb[ng * 256 + mg]) = p;
      } else if constexpr (EPI == EPI_BIAS_F16){
        f16* Ohb = Oh + (long)b * 65536;
#pragma unroll
        for (int r = 0; r < 4; r++) Ohb[(mg + r) * 256 + ng] = (f16)(v[r] + bias[mg + r]);
      } else if constexpr (EPI == EPI_PV_DT){
        const float* Ub = U + (long)b * 65536;
        f16* Ohb = Oh + (long)b * 65536;
        f16x4 p;
#pragma unroll
        for (int r = 0; r < 4; r++) p[r] = (f16)(Ub[(mg + r) * 256 + ng] - v[r]);
        *(f16x4*)(&Ohb[ng * 256 + mg]) = p;
      }
    }
  }
}

// ---------------- per softmax-row stats: mx, rs = 1/sum(exp) ----------------
// E batch stride is 262144 (E lives inside d_out's [B][1024][256] layout)!
__global__ __launch_bounds__(256) void rowstat_k(const float* __restrict__ E,
                                                 float* __restrict__ mx, float* __restrict__ rs){
  int rid = blockIdx.x * 4 + (threadIdx.x >> 6);
  int lane = threadIdx.x & 63;
  int b = rid >> 8, n = rid & 255;
  const float* row = E + (long)b * 262144 + n * 256;
  float v[4];
  float m = -1e30f;
#pragma unroll
  for (int i = 0; i < 4; i++){ v[i] = row[lane + 64 * i]; m = fmaxf(m, v[i]); }
  for (int off = 32; off > 0; off >>= 1) m = fmaxf(m, __shfl_xor(m, off));
  float s = 0.f;
#pragma unroll
  for (int i = 0; i < 4; i++) s += __expf(v[i] - m);
  for (int off = 32; off > 0; off >>= 1) s += __shfl_xor(s, off);
  if (lane == 0){ mx[rid] = m; rs[rid] = 1.f / s; }
}

// ---------------- attnT[b][m][n] = exp(E[b][m][n]-mx[bn])*rs[bn] / (eps + rowsum), fp16 ----------------
// uses E symmetry (E[m][n] == E[n][m]) -> pure row-major pass, colsum == own row-sum
__global__ __launch_bounds__(256) void renorm_k(const float* __restrict__ E,
                                                const float* __restrict__ mx,
                                                const float* __restrict__ rs,
                                                f16* __restrict__ AT){
  int rid = blockIdx.x * 4 + (threadIdx.x >> 6);   // b*256 + m
  int lane = threadIdx.x & 63;
  int b = rid >> 8, m = rid & 255;
  const float* row = E + (long)b * 262144 + m * 256;  // batch stride 262144!
  const float* mxb = mx + (b << 8);
  const float* rsb = rs + (b << 8);
  float tv[4];
  float cs = 0.f;
#pragma unroll
  for (int i = 0; i < 4; i++){
    int n = lane + 64 * i;
    tv[i] = __expf(row[n] - mxb[n]) * rsb[n];
    cs += tv[i];
  }
  for (int off = 32; off > 0; off >>= 1) cs += __shfl_xor(cs, off);
  float inv = 1.f / (1e-9f + cs);
  f16* orow = AT + (long)rid * 256;
#pragma unroll
  for (int i = 0; i < 4; i++) orow[lane + 64 * i] = (f16)(tv[i] * inv);
}

// ---------------- BN stats per channel over (B, N) ----------------
__global__ __launch_bounds__(256) void bn_stats_k(const float* __restrict__ Y,
                                                  float* __restrict__ mean, float* __restrict__ rstd){
  int c = blockIdx.x, t = threadIdx.x;
  float s = 0.f, q = 0.f;
  const float* p = Y + c * 256 + t;
  for (int b = 0; b < 256; b++){ float v = p[(long)b * 65536]; s += v; q += v * v; }
  for (int off = 32; off > 0; off >>= 1){ s += __shfl_down(s, off); q += __shfl_down(q, off); }
  __shared__ float ss[4], qq[4];
  int lane = t & 63, w = t >> 6;
  if (lane == 0){ ss[w] = s; qq[w] = q; }
  __syncthreads();
  if (t == 0){
    float S = ss[0] + ss[1] + ss[2] + ss[3];
    float Q = qq[0] + qq[1] + qq[2] + qq[3];
    float m = S * (1.f / 65536.f);
    float var = Q * (1.f / 65536.f) - m * m;
    mean[c] = m;
    rstd[c] = rsqrtf(var + 1e-5f);
  }
}

// ---------------- BN apply + relu (+2x residual) + layout writes ----------------
template<bool RESID, bool WN32, bool WT32, bool WN16, bool WT16, bool WDOUT>
__global__ __launch_bounds__(256) void bn_apply_k(
    const float* __restrict__ Y, const float* __restrict__ U,
    const float* __restrict__ mean, const float* __restrict__ rstd,
    const float* __restrict__ gamma, const float* __restrict__ beta,
    float* __restrict__ on32, float* __restrict__ ot32,
    f16* __restrict__ on16, f16* __restrict__ ot16,
    float* __restrict__ odout)
{
  __shared__ float tile[64][65];
  int b = blockIdx.z, c0 = blockIdx.y * 64, n0 = blockIdx.x * 64;
  int t = threadIdx.x, nl = t & 63, cr = t >> 6;
  long base = (long)b * 65536;
#pragma unroll
  for (int i = 0; i < 16; i++){
    int cl = cr + 4 * i;
    int c = c0 + cl, n = n0 + nl;
    long idx = base + c * 256 + n;
    float y = Y[idx];
    float v = fmaxf((y - mean[c]) * rstd[c] * gamma[c] + beta[c], 0.f);
    if constexpr (RESID) v += 2.f * U[idx];
    if constexpr (WN32) on32[idx] = v;
    if constexpr (WN16) on16[idx] = (f16)v;
    if constexpr (WDOUT) odout[(long)b * 262144 + c * 256 + n] = v;
    if constexpr (WT32 || WT16) tile[cl][nl] = v;
  }
  if constexpr (WT32 || WT16){
    __syncthreads();
    int cl2 = t & 63, nr2 = t >> 6;
#pragma unroll
    for (int i = 0; i < 16; i++){
      int nl2 = nr2 + 4 * i;
      long tidx = base + (n0 + nl2) * 256 + (c0 + cl2);
      float v = tile[cl2][nl2];
      if constexpr (WT32) ot32[tidx] = v;
      if constexpr (WT16) ot16[tidx] = (f16)v;
    }
  }
}

extern "C" void kernel_launch(void* const* d_in, const int* in_sizes, int n_in,
                              void* d_out, int out_size, void* d_ws, size_t ws_size,
                              hipStream_t stream)
{
  (void)in_sizes; (void)n_in; (void)out_size; (void)ws_size;

  const float* x0  = (const float*)d_in[0];
  const float* cw  = (const float*)d_in[1];
  const float* bng = (const float*)d_in[2];
  const float* bnb = (const float*)d_in[3];
  const float* wqk = (const float*)d_in[4];
  const float* wv  = (const float*)d_in[5];
  const float* bv  = (const float*)d_in[6];
  const float* wt  = (const float*)d_in[7];
  const float* bt  = (const float*)d_in[8];
  const float* sag = (const float*)d_in[9];
  const float* sab = (const float*)d_in[10];

  const long T = 16777216; // elements per [B,C,N] tensor
  float* Un0 = (float*)d_ws;       // u (f32, normal) even slots
  float* Un1 = Un0 + T;            // u (f32, normal) odd slots
  float* F1  = Un1 + T;            // pre-BN GEMM output f32
  f16*  Ht   = (f16*)(F1 + T);     // uT fp16 (GEMM BT operand)
  f16*  XK   = Ht + T;             // xkT, then xv
  f16*  ATb  = XK + T;             // attnT fp16
  f16*  DT   = ATb + T;            // dT fp16
  f16*  Wc   = DT + T;
  f16*  Wq   = Wc + 6 * 65536;
  f16*  Wv_  = Wq + 8 * 65536;
  f16*  Wt_  = Wv_ + 8 * 65536;
  float* mx  = (float*)(Wt_ + 8 * 65536);
  float* rs  = mx + 65536;
  float* mn  = rs + 65536;
  float* rsd = mn + 256;
  float* E   = (float*)d_out + 196608; // d_out region 3 as energy scratch (batch stride 262144!)

  dim3 thr(256);
  dim3 gg(2, 2, 256);
  dim3 tile(4, 4, 256);

  cast_f16_k<<<dim3(384), thr, 0, stream>>>(cw,  Wc,  6 * 65536);
  cast_f16_k<<<dim3(512), thr, 0, stream>>>(wqk, Wq,  8 * 65536);
  cast_f16_k<<<dim3(512), thr, 0, stream>>>(wv,  Wv_, 8 * 65536);
  cast_f16_k<<<dim3(512), thr, 0, stream>>>(wt,  Wt_, 8 * 65536);
  transpose_f16_k<<<tile, thr, 0, stream>>>(x0, Ht);

  // conv0: x = relu(bn(W x)) -> only xT fp16 needed
  gemm_f16<EPI_EF32><<<gg, thr, 0, stream>>>(Wc, 0, Ht, F1, 65536, nullptr, nullptr, nullptr);
  bn_stats_k<<<256, thr, 0, stream>>>(F1, mn, rsd);
  bn_apply_k<false, false, false, false, true, false><<<tile, thr, 0, stream>>>(
      F1, nullptr, mn, rsd, bng, bnb, nullptr, nullptr, nullptr, Ht, nullptr);
  // conv1: -> Un0 (residual) + Ht
  gemm_f16<EPI_EF32><<<gg, thr, 0, stream>>>(Wc + 65536, 0, Ht, F1, 65536, nullptr, nullptr, nullptr);
  bn_stats_k<<<256, thr, 0, stream>>>(F1, mn, rsd);
  bn_apply_k<false, true, false, false, true, false><<<tile, thr, 0, stream>>>(
      F1, nullptr, mn, rsd, bng + 256, bnb + 256, Un0, nullptr, nullptr, Ht, nullptr);

  for (int blk = 0; blk < 4; blk++){
    for (int s = 0; s < 2; s++){
      int li = 2 * blk + s;
      float* u = (s == 0) ? Un0 : Un1;
      // xkT = (wqk u)^T fp16
      gemm_f16<EPI_T16><<<gg, thr, 0, stream>>>(Wq + li * 65536, 0, Ht, nullptr, 0, XK, nullptr, nullptr);
      // E[n][m] = <xk_n, xk_m> f32 (symmetric), batch stride 262144
      gemm_f16<EPI_EF32><<<gg, thr, 0, stream>>>(XK, 65536, XK, E, 262144, nullptr, nullptr, nullptr);
      rowstat_k<<<dim3(16384), thr, 0, stream>>>(E, mx, rs);
      renorm_k<<<dim3(16384), thr, 0, stream>>>(E, mx, rs, ATb);
      // xv = wv u + bv, fp16 normal (reuse XK)
      gemm_f16<EPI_BIAS_F16><<<gg, thr, 0, stream>>>(Wv_ + li * 65536, 0, Ht, nullptr, 0, XK, bv + li * 256, nullptr);
      // dT = (u - xv attn')^T fp16
      gemm_f16<EPI_PV_DT><<<gg, thr, 0, stream>>>(XK, 65536, ATb, nullptr, 0, DT, nullptr, u);
      // y = wt d + bt -> F1 f32
      gemm_f16<EPI_BIAS_F32><<<gg, thr, 0, stream>>>(Wt_ + li * 65536, 0, DT, F1, 65536, nullptr, bt + li * 256, nullptr);
      bn_stats_k<<<256, thr, 0, stream>>>(F1, mn, rsd);
      if (s == 0){
        // x1 = 2u + relu(bn(y)); Ht <- x1 (next uT), Un1 <- x1^T (next u)
        bn_apply_k<true, false, true, true, false, false><<<tile, thr, 0, stream>>>(
            F1, u, mn, rsd, sag + li * 256, sab + li * 256, nullptr, Un1, Ht, nullptr, nullptr);
      } else {
        // x11pre = 2u + relu(bn(y)); Ht <- (x11pre)^T (conv BT operand)
        bn_apply_k<true, false, false, false, true, false><<<tile, thr, 0, stream>>>(
            F1, u, mn, rsd, sag + li * 256, sab + li * 256, nullptr, nullptr, nullptr, Ht, nullptr);
      }
    }
    // block conv + bn + relu -> d_out region blk, Un0 (next u), Ht (next uT)
    gemm_f16<EPI_EF32><<<gg, thr, 0, stream>>>(Wc + (blk + 2) * 65536, 0, Ht, F1, 65536, nullptr, nullptr, nullptr);
    bn_stats_k<<<256, thr, 0, stream>>>(F1, mn, rsd);
    bn_apply_k<false, true, false, false, true, true><<<tile, thr, 0, stream>>>(
        F1, nullptr, mn, rsd, bng + (blk + 2) * 256, bnb + (blk + 2) * 256,
        Un0, nullptr, nullptr, Ht, (float*)d_out + blk * 65536);
  }
}